// Round 3
// baseline (375.785 us; speedup 1.0000x reference)
//
#include <hip/hip_runtime.h>
#include <hip/hip_bf16.h>

typedef __bf16 bf16;
typedef __bf16 bf16x4 __attribute__((ext_vector_type(4)));
typedef __bf16 bf16x8 __attribute__((ext_vector_type(8)));
typedef float f32x4 __attribute__((ext_vector_type(4)));

#define MFMA16(a, b, c) __builtin_amdgcn_mfma_f32_16x16x32_bf16(a, b, c, 0, 0, 0)

constexpr int DIM = 1024;
constexpr int NH = 16;
constexpr int HD = 64;
constexpr float SCALE = 0.125f;
constexpr float L2E = 1.4426950408889634f;
constexpr float SCL2E = SCALE * L2E;  // folded into Q-proj epilogue

// raw v_exp_f32 — bypass the denorm-guarded exp2f lowering (input range here is
// |x| < ~40, far from the guard region, so the raw instruction is exact enough)
__device__ __forceinline__ float fast_exp2(float x) {
  float r;
  asm("v_exp_f32 %0, %1" : "=v"(r) : "v"(x));
  return r;
}

// async global->LDS, 16B per lane; lane i deposits at ldsbase + i*16
__device__ __forceinline__ void gl_lds16(const void* g, void* l) {
  __builtin_amdgcn_global_load_lds((const __attribute__((address_space(1))) void*)g,
                                   (__attribute__((address_space(3))) void*)l, 16, 0, 0);
}

// ---------------------------------------------------------------------------
// fp32 -> bf16 conversion (memory-bound, vectorized 8/thread)
// ---------------------------------------------------------------------------
__global__ __launch_bounds__(256) void cvt_f32_bf16(const float* __restrict__ s,
                                                    bf16* __restrict__ d, int n8) {
  const int i = blockIdx.x * 256 + threadIdx.x;
  if (i < n8) {
    const float4 v0 = ((const float4*)s)[i * 2];
    const float4 v1 = ((const float4*)s)[i * 2 + 1];
    bf16x8 o = {(bf16)v0.x, (bf16)v0.y, (bf16)v0.z, (bf16)v0.w,
                (bf16)v1.x, (bf16)v1.y, (bf16)v1.z, (bf16)v1.w};
    ((bf16x8*)d)[i] = o;
  }
}

// all 4 weight matrices in one launch; dst regions are contiguous in ws
__global__ __launch_bounds__(256) void cvt_w4(const float* __restrict__ a,
                                              const float* __restrict__ b,
                                              const float* __restrict__ c,
                                              const float* __restrict__ d,
                                              bf16* __restrict__ o) {
  constexpr int N8 = DIM * DIM / 8;  // 131072 (pow2)
  const int i = blockIdx.x * 256 + threadIdx.x;  // grid covers 4*N8 exactly
  const int g = i >> 17;
  const int j = i & (N8 - 1);
  const float* s = (g == 0) ? a : (g == 1) ? b : (g == 2) ? c : d;
  const float4 v0 = ((const float4*)s)[j * 2];
  const float4 v1 = ((const float4*)s)[j * 2 + 1];
  bf16x8 ov = {(bf16)v0.x, (bf16)v0.y, (bf16)v0.z, (bf16)v0.w,
               (bf16)v1.x, (bf16)v1.y, (bf16)v1.z, (bf16)v1.w};
  ((bf16x8*)o)[i] = ov;
}

// ---------------------------------------------------------------------------
// bf16 NT GEMM, m97 structure: global_load_lds staging + XOR swizzle.
// C[M,1024] = (A[M,1024] @ W[1024,1024]^T + bias) * oscale
// OUT_MODE 0: fp32 row-major; 1: bf16 head-major [B,NH,Lq,64];
// OUT_MODE 3: V^T flipped orientation — A=Wv (rows=d), W=x_low (rows=token),
//             bias indexed by ROW, out[((tok>>10)*1024 + row)*1024 + (tok&1023)]
//             -> coalesced 32B runs instead of 2KB-stride 2B scatter.
// Swizzle: 16B chunk qc of tile-row r lives at LDS slot (r, qc ^ (r&7)).
// ---------------------------------------------------------------------------
template <int OUT_MODE>
__global__ __launch_bounds__(256) void gemm_bf16(const bf16* __restrict__ A,
                                                 const bf16* __restrict__ W,
                                                 const float* __restrict__ bias,
                                                 void* __restrict__ Cptr, int Lq,
                                                 float oscale) {
  __shared__ bf16 As[128 * 64];
  __shared__ bf16 Bs[128 * 64];

  const int bm = blockIdx.x * 128;
  const int bn = blockIdx.y * 128;
  const int tid = threadIdx.x;
  const int w = tid >> 6;
  const int lane = tid & 63;
  const int quad = lane >> 4;
  const int l16 = lane & 15;
  const int wm = (w >> 1) * 64;
  const int wn = (w & 1) * 64;
  const int lr = lane >> 3;                 // row offset within a stage call
  const int sc8 = (((lane & 7) ^ lr)) << 3; // swizzled source chunk (elems)
  const int x7 = l16 & 7;

  // per-lane global element offsets for the 4 stage rounds (A and B)
  size_t aOff[4], bOff[4];
#pragma unroll
  for (int r = 0; r < 4; ++r) {
    const int rowt = (r * 4 + w) * 8 + lr;
    aOff[r] = (size_t)(bm + rowt) * DIM + sc8;
    bOff[r] = (size_t)(bn + rowt) * DIM + sc8;
  }

  f32x4 acc[4][4] = {};

  for (int k0 = 0; k0 < DIM; k0 += 64) {
#pragma unroll
    for (int r = 0; r < 4; ++r) {
      gl_lds16(A + aOff[r] + k0, (char*)As + (r * 4 + w) * 1024);
      gl_lds16(W + bOff[r] + k0, (char*)Bs + (r * 4 + w) * 1024);
    }
    __syncthreads();  // vmcnt(0) drain -> tile resident

#pragma unroll
    for (int s = 0; s < 2; ++s) {
      bf16x8 af[4], bfr[4];
#pragma unroll
      for (int mi = 0; mi < 4; ++mi)
        af[mi] = *(const bf16x8*)((char*)As + (wm + mi * 16 + l16) * 128 +
                                  (((quad + 4 * s) ^ x7) << 4));
#pragma unroll
      for (int ni = 0; ni < 4; ++ni)
        bfr[ni] = *(const bf16x8*)((char*)Bs + (wn + ni * 16 + l16) * 128 +
                                   (((quad + 4 * s) ^ x7) << 4));
#pragma unroll
      for (int mi = 0; mi < 4; ++mi)
#pragma unroll
        for (int ni = 0; ni < 4; ++ni)
          acc[mi][ni] = MFMA16(af[mi], bfr[ni], acc[mi][ni]);
    }
    __syncthreads();  // reads done before next overwrite
  }

#pragma unroll
  for (int mi = 0; mi < 4; ++mi) {
#pragma unroll
    for (int ni = 0; ni < 4; ++ni) {
      const int col = bn + wn + ni * 16 + l16;
      const float bv = (OUT_MODE == 3) ? 0.f : bias[col];
#pragma unroll
      for (int r = 0; r < 4; ++r) {
        const int row = bm + wm + mi * 16 + quad * 4 + r;
        if constexpr (OUT_MODE == 0) {
          const float val = (acc[mi][ni][r] + bv) * oscale;
          ((float*)Cptr)[(size_t)row * DIM + col] = val;
        } else if constexpr (OUT_MODE == 1) {
          const float val = (acc[mi][ni][r] + bv) * oscale;
          const int b = row / Lq;
          const int l = row - b * Lq;
          ((bf16*)Cptr)[((size_t)((b * NH + (col >> 6)) * Lq + l) << 6) + (col & 63)] =
              (bf16)val;
        } else {  // OUT_MODE 3: V^T, row = d-index, col = global token
          const float val = acc[mi][ni][r] + bias[row];
          const int bb = col >> 10;
          const int kv = col & 1023;
          ((bf16*)Cptr)[((size_t)(bb * 1024 + row)) * 1024 + kv] = (bf16)val;
        }
      }
    }
  }
}

// ---------------------------------------------------------------------------
// Legacy fp32-input GEMM (R3) — fallback when ws is too small for bf16 path.
// ---------------------------------------------------------------------------
template <int OUT_MODE, bool A_BF16>
__global__ __launch_bounds__(256) void gemm_nt(const void* __restrict__ Aptr,
                                               const float* __restrict__ W,
                                               const float* __restrict__ bias,
                                               void* __restrict__ Cptr, int Lq,
                                               float oscale) {
  constexpr int LDT = 72;
  __shared__ bf16 As[128 * LDT];
  __shared__ bf16 Bs[128 * LDT];

  const int bm = blockIdx.x * 128;
  const int bn = blockIdx.y * 128;
  const int tid = threadIdx.x;
  const int w = tid >> 6;
  const int lane = tid & 63;
  const int quad = lane >> 4;
  const int l16 = lane & 15;
  const int wm = (w >> 1) * 64;
  const int wn = (w & 1) * 64;

  f32x4 acc[4][4] = {};

  for (int k0 = 0; k0 < DIM; k0 += 64) {
#pragma unroll
    for (int i = 0; i < 8; ++i) {
      int f = i * 256 + tid;
      int row = f >> 4;
      int c4 = (f & 15) << 2;
      const float4 v = *(const float4*)(W + (size_t)(bn + row) * DIM + k0 + c4);
      bf16x4 bv = {(bf16)v.x, (bf16)v.y, (bf16)v.z, (bf16)v.w};
      *(bf16x4*)&Bs[row * LDT + c4] = bv;
    }
    if constexpr (A_BF16) {
      const bf16* Ab = (const bf16*)Aptr;
#pragma unroll
      for (int i = 0; i < 4; ++i) {
        int f = i * 256 + tid;
        int row = f >> 3;
        int c8 = (f & 7) << 3;
        *(bf16x8*)&As[row * LDT + c8] =
            *(const bf16x8*)(Ab + (size_t)(bm + row) * DIM + k0 + c8);
      }
    } else {
      const float* Af = (const float*)Aptr;
#pragma unroll
      for (int i = 0; i < 8; ++i) {
        int f = i * 256 + tid;
        int row = f >> 4;
        int c4 = (f & 15) << 2;
        const float4 v = *(const float4*)(Af + (size_t)(bm + row) * DIM + k0 + c4);
        bf16x4 av = {(bf16)v.x, (bf16)v.y, (bf16)v.z, (bf16)v.w};
        *(bf16x4*)&As[row * LDT + c4] = av;
      }
    }
    __syncthreads();

#pragma unroll
    for (int sub = 0; sub < 2; ++sub) {
      bf16x8 af[4], bfr[4];
#pragma unroll
      for (int mi = 0; mi < 4; ++mi)
        af[mi] = *(const bf16x8*)&As[(wm + mi * 16 + l16) * LDT + sub * 32 + quad * 8];
#pragma unroll
      for (int ni = 0; ni < 4; ++ni)
        bfr[ni] = *(const bf16x8*)&Bs[(wn + ni * 16 + l16) * LDT + sub * 32 + quad * 8];
#pragma unroll
      for (int mi = 0; mi < 4; ++mi)
#pragma unroll
        for (int ni = 0; ni < 4; ++ni)
          acc[mi][ni] = MFMA16(af[mi], bfr[ni], acc[mi][ni]);
    }
    __syncthreads();
  }

#pragma unroll
  for (int mi = 0; mi < 4; ++mi) {
#pragma unroll
    for (int ni = 0; ni < 4; ++ni) {
      const int col = bn + wn + ni * 16 + l16;
      const float bv = bias[col];
#pragma unroll
      for (int r = 0; r < 4; ++r) {
        const int row = bm + wm + mi * 16 + quad * 4 + r;
        const float val = (acc[mi][ni][r] + bv) * oscale;
        if constexpr (OUT_MODE == 0) {
          ((float*)Cptr)[(size_t)row * DIM + col] = val;
        } else if constexpr (OUT_MODE == 1) {
          const int b = row / Lq;
          const int l = row - b * Lq;
          ((bf16*)Cptr)[((size_t)((b * NH + (col >> 6)) * Lq + l) << 6) + (col & 63)] =
              (bf16)val;
        } else {
          const int b = row >> 10;
          const int kv = row & 1023;
          ((bf16*)Cptr)[(((size_t)(b * NH + (col >> 6)) << 6) + (col & 63)) * 1024 + kv] =
              (bf16)val;
        }
      }
    }
  }
}

// ---------------------------------------------------------------------------
// Flash cross-attention, transposed formulation, LDS-staged K/V.
//   S^T = K Q^T ; O^T = V^T P^T. 256 q rows/block, 4 waves x 4 q-groups.
//   Wider q per block: staging, K/V-fragment LDS reads, and barriers are
//   per-tile costs shared across q -> per-FLOP LDS traffic drops 33%.
//   Q pre-scaled by SCALE*log2(e); denominator via ones-MFMA on matrix pipe.
// grid (4096/256, NH, B), 256 threads.
// ---------------------------------------------------------------------------
__global__ __launch_bounds__(256) void attn_fused(const bf16* __restrict__ Q,
                                                  const bf16* __restrict__ K,
                                                  const bf16* __restrict__ VT,
                                                  bf16* __restrict__ O) {
  __shared__ bf16 Ks[2][64 * 64];
  __shared__ bf16 Vs[2][64 * 64];
  __shared__ bf16 Ps[4 * 16 * 64];  // per-wave 16x64, swizzled, group-shared

  const int qt = blockIdx.x;
  const int h = blockIdx.y;
  const int b = blockIdx.z;
  const int tid = threadIdx.x;
  const int w = tid >> 6;
  const int lane = tid & 63;
  const int quad = lane >> 4;
  const int l16 = lane & 15;
  const int lr = lane >> 3;
  const int sc8 = (((lane & 7) ^ lr)) << 3;
  const int x7 = l16 & 7;

  const bf16* Qp =
      Q + ((size_t)(b * NH + h) * 4096 + qt * 256 + w * 64 + l16) * HD + quad * 8;
  const bf16* Kb = K + (size_t)(b * NH + h) * 1024 * HD;
  const bf16* Vb = VT + (size_t)(b * NH + h) * HD * 1024;

  bf16x8 qf[4][2];
#pragma unroll
  for (int g = 0; g < 4; ++g)
#pragma unroll
    for (int s = 0; s < 2; ++s) qf[g][s] = *(const bf16x8*)(Qp + g * 16 * HD + s * 32);

  char* pw = (char*)&Ps[w * 16 * 64];

  f32x4 oacc[4][4] = {};
  f32x4 lacc[4] = {};  // softmax denominator, accumulated on MFMA pipe

  bf16x8 ones;
#pragma unroll
  for (int i = 0; i < 8; ++i) ones[i] = (bf16)1.0f;

  auto stage = [&](int kt, int bi) {
#pragma unroll
    for (int c2 = 0; c2 < 2; ++c2) {
      const int c = c2 * 4 + w;
      gl_lds16(Kb + (size_t)(kt + c * 8 + lr) * HD + sc8, (char*)&Ks[bi][0] + c * 1024);
      gl_lds16(Vb + (size_t)(c * 8 + lr) * 1024 + kt + sc8, (char*)&Vs[bi][0] + c * 1024);
    }
  };

  stage(0, 0);
  int buf = 0;
  for (int kt = 0; kt < 1024; kt += 64) {
    __syncthreads();  // drains this tile's global_load_lds (vmcnt0) + syncs waves
    if (kt + 64 < 1024) stage(kt + 64, buf ^ 1);

    // ---- K fragments (shared by all q-groups), swizzled LDS reads
    bf16x8 kf[4][2];
#pragma unroll
    for (int nt = 0; nt < 4; ++nt)
#pragma unroll
      for (int s = 0; s < 2; ++s)
        kf[nt][s] = *(const bf16x8*)((char*)&Ks[buf][0] + (nt * 16 + l16) * 128 +
                                     (((quad + 4 * s) ^ x7) << 4));

    // ---- per group: S^T + exp2 + swizzled P store, then P^T B-fragments
    bf16x8 pf[4][2];
#pragma unroll
    for (int g = 0; g < 4; ++g) {
      __builtin_amdgcn_s_setprio(1);
#pragma unroll
      for (int nt = 0; nt < 4; ++nt) {
        f32x4 a = {0.f, 0.f, 0.f, 0.f};
        a = MFMA16(kf[nt][0], qf[g][0], a);
        a = MFMA16(kf[nt][1], qf[g][1], a);
        bf16x4 pb;
#pragma unroll
        for (int r = 0; r < 4; ++r) pb[r] = (bf16)fast_exp2(a[r]);
        *(bf16x4*)(pw + l16 * 128 + ((nt * 32 + quad * 8) ^ (x7 << 4))) = pb;
      }
      __builtin_amdgcn_s_setprio(0);
#pragma unroll
      for (int s = 0; s < 2; ++s)
        pf[g][s] = *(const bf16x8*)(pw + l16 * 128 + ((s * 64 + quad * 16) ^ (x7 << 4)));
      // denominator: l[q] += sum_kv P (rows of C all identical = column sums)
      lacc[g] = MFMA16(ones, pf[g][0], lacc[g]);
      lacc[g] = MFMA16(ones, pf[g][1], lacc[g]);
    }

    // ---- V^T fragments + O^T += V^T P^T
    __builtin_amdgcn_s_setprio(1);
#pragma unroll
    for (int dt = 0; dt < 4; ++dt) {
      bf16x8 vf0 = *(const bf16x8*)((char*)&Vs[buf][0] + (dt * 16 + l16) * 128 +
                                    ((quad ^ x7) << 4));
      bf16x8 vf1 = *(const bf16x8*)((char*)&Vs[buf][0] + (dt * 16 + l16) * 128 +
                                    ((((quad + 4)) ^ x7) << 4));
#pragma unroll
      for (int g = 0; g < 4; ++g) {
        oacc[g][dt] = MFMA16(vf0, pf[g][0], oacc[g][dt]);
        oacc[g][dt] = MFMA16(vf1, pf[g][1], oacc[g][dt]);
      }
    }
    __builtin_amdgcn_s_setprio(0);
    buf ^= 1;
  }

  // ---- finalize (lacc rows are identical: every lane already holds its
  // column's full denominator — no cross-lane reduce needed)
#pragma unroll
  for (int g = 0; g < 4; ++g) {
    const float inv = 1.f / lacc[g][0];
    const size_t orow =
        ((size_t)(b * 4096 + qt * 256 + w * 64 + g * 16 + l16)) * DIM + h * 64;
#pragma unroll
    for (int dt = 0; dt < 4; ++dt) {
      bf16x4 ov = {(bf16)(oacc[g][dt][0] * inv), (bf16)(oacc[g][dt][1] * inv),
                   (bf16)(oacc[g][dt][2] * inv), (bf16)(oacc[g][dt][3] * inv)};
      *(bf16x4*)(O + orow + dt * 16 + quad * 4) = ov;
    }
  }
}

// ---------------------------------------------------------------------------
extern "C" void kernel_launch(void* const* d_in, const int* in_sizes, int n_in,
                              void* d_out, int out_size, void* d_ws, size_t ws_size,
                              hipStream_t stream) {
  const float* x_broad = (const float*)d_in[0];
  const float* x_low = (const float*)d_in[1];
  const float* Wq = (const float*)d_in[2];
  const float* bq = (const float*)d_in[3];
  const float* Wk = (const float*)d_in[4];
  const float* bk = (const float*)d_in[5];
  const float* Wv = (const float*)d_in[6];
  const float* bv = (const float*)d_in[7];
  const float* Wo = (const float*)d_in[8];
  const float* bo = (const float*)d_in[9];

  constexpr int B = 4, L = 4096, LL = 1024;
  const size_t qBytes = (size_t)B * NH * L * HD * 2;    // 33.55 MB
  const size_t kvBytes = (size_t)B * NH * LL * HD * 2;  //  8.39 MB
  const size_t oBytes = qBytes;                          // 33.55 MB (O / xb_bf alias)
  const size_t xlBytes = kvBytes;                        //  8.39 MB
  const size_t wBytes = (size_t)DIM * DIM * 2;           //  2.10 MB each

  char* ws = (char*)d_ws;
  bf16* Qw = (bf16*)ws;
  bf16* Kw = (bf16*)(ws + qBytes);
  bf16* Vw = (bf16*)(ws + qBytes + kvBytes);
  bf16* Ow = (bf16*)(ws + qBytes + 2 * kvBytes);

  const dim3 blk(256);
  const size_t need = qBytes + 2 * kvBytes + oBytes + xlBytes + 4 * wBytes;

  if (ws_size >= need) {
    // bf16 fast path: Ow region doubles as xb_bf (consumed by Q-proj before attn writes O)
    bf16* xbB = Ow;
    bf16* xlB = (bf16*)(ws + qBytes + 2 * kvBytes + oBytes);
    bf16* WqB = (bf16*)(ws + qBytes + 2 * kvBytes + oBytes + xlBytes);
    bf16* WkB = WqB + (size_t)DIM * DIM;
    bf16* WvB = WkB + (size_t)DIM * DIM;
    bf16* WoB = WvB + (size_t)DIM * DIM;

    hipLaunchKernelGGL(cvt_f32_bf16, dim3(B * L * DIM / 8 / 256), blk, 0, stream,
                       x_broad, xbB, B * L * DIM / 8);
    hipLaunchKernelGGL(cvt_f32_bf16, dim3(B * LL * DIM / 8 / 256), blk, 0, stream,
                       x_low, xlB, B * LL * DIM / 8);
    hipLaunchKernelGGL(cvt_w4, dim3(4 * DIM * DIM / 8 / 256), blk, 0, stream, Wq, Wk,
                       Wv, Wo, WqB);

    // Q-projection carries the softmax scale (SCALE*log2e) in its epilogue
    hipLaunchKernelGGL((gemm_bf16<1>), dim3(B * L / 128, DIM / 128), blk, 0, stream,
                       xbB, WqB, bq, Qw, L, SCL2E);
    hipLaunchKernelGGL((gemm_bf16<1>), dim3(B * LL / 128, DIM / 128), blk, 0, stream,
                       xlB, WkB, bk, Kw, LL, 1.0f);
    // V^T via flipped orientation: A = Wv (rows=d), B = x_low (rows=token)
    hipLaunchKernelGGL((gemm_bf16<3>), dim3(DIM / 128, B * LL / 128), blk, 0, stream,
                       WvB, xlB, bv, Vw, LL, 1.0f);
    hipLaunchKernelGGL(attn_fused, dim3(L / 256, NH, B), blk, 0, stream, Qw, Kw, Vw, Ow);
    hipLaunchKernelGGL((gemm_bf16<0>), dim3(B * L / 128, DIM / 128), blk, 0, stream,
                       Ow, WoB, bo, d_out, 1, 1.0f);
  } else {
    // fallback: fp32-input GEMMs (R3), same attention
    hipLaunchKernelGGL((gemm_nt<1, false>), dim3(B * L / 128, DIM / 128), blk, 0,
                       stream, x_broad, Wq, bq, Qw, L, SCL2E);
    hipLaunchKernelGGL((gemm_nt<1, false>), dim3(B * LL / 128, DIM / 128), blk, 0,
                       stream, x_low, Wk, bk, Kw, LL, 1.0f);
    hipLaunchKernelGGL((gemm_nt<2, false>), dim3(B * LL / 128, DIM / 128), blk, 0,
                       stream, x_low, Wv, bv, Vw, LL, 1.0f);
    hipLaunchKernelGGL(attn_fused, dim3(L / 256, NH, B), blk, 0, stream, Qw, Kw, Vw, Ow);
    hipLaunchKernelGGL((gemm_nt<0, true>), dim3(B * L / 128, DIM / 128), blk, 0,
                       stream, Ow, Wo, bo, d_out, 1, 1.0f);
  }
}

// Round 4
// 371.003 us; speedup vs baseline: 1.0129x; 1.0129x over previous
//
#include <hip/hip_runtime.h>
#include <hip/hip_bf16.h>

typedef __bf16 bf16;
typedef __bf16 bf16x4 __attribute__((ext_vector_type(4)));
typedef __bf16 bf16x8 __attribute__((ext_vector_type(8)));
typedef float f32x4 __attribute__((ext_vector_type(4)));

#define MFMA16(a, b, c) __builtin_amdgcn_mfma_f32_16x16x32_bf16(a, b, c, 0, 0, 0)

constexpr int DIM = 1024;
constexpr int NH = 16;
constexpr int HD = 64;
constexpr float SCALE = 0.125f;
constexpr float L2E = 1.4426950408889634f;
constexpr float SCL2E = SCALE * L2E;  // folded into Q-proj epilogue

constexpr int ilog2(int v) {
  int s = 0;
  while ((1 << s) < v) ++s;
  return s;
}

// raw v_exp_f32 — bypass the denorm-guarded exp2f lowering (input range here is
// |x| < ~40, far from the guard region, so the raw instruction is exact enough)
__device__ __forceinline__ float fast_exp2(float x) {
  float r;
  asm("v_exp_f32 %0, %1" : "=v"(r) : "v"(x));
  return r;
}

// async global->LDS, 16B per lane; lane i deposits at ldsbase + i*16
__device__ __forceinline__ void gl_lds16(const void* g, void* l) {
  __builtin_amdgcn_global_load_lds((const __attribute__((address_space(1))) void*)g,
                                   (__attribute__((address_space(3))) void*)l, 16, 0, 0);
}

// ---------------------------------------------------------------------------
// fp32 -> bf16 conversion (memory-bound, vectorized 8/thread)
// ---------------------------------------------------------------------------
__global__ __launch_bounds__(256) void cvt_f32_bf16(const float* __restrict__ s,
                                                    bf16* __restrict__ d, int n8) {
  const int i = blockIdx.x * 256 + threadIdx.x;
  if (i < n8) {
    const float4 v0 = ((const float4*)s)[i * 2];
    const float4 v1 = ((const float4*)s)[i * 2 + 1];
    bf16x8 o = {(bf16)v0.x, (bf16)v0.y, (bf16)v0.z, (bf16)v0.w,
                (bf16)v1.x, (bf16)v1.y, (bf16)v1.z, (bf16)v1.w};
    ((bf16x8*)d)[i] = o;
  }
}

// all 4 weight matrices in one launch; dst regions are contiguous in ws
__global__ __launch_bounds__(256) void cvt_w4(const float* __restrict__ a,
                                              const float* __restrict__ b,
                                              const float* __restrict__ c,
                                              const float* __restrict__ d,
                                              bf16* __restrict__ o) {
  constexpr int N8 = DIM * DIM / 8;  // 131072 (pow2)
  const int i = blockIdx.x * 256 + threadIdx.x;  // grid covers 4*N8 exactly
  const int g = i >> 17;
  const int j = i & (N8 - 1);
  const float* s = (g == 0) ? a : (g == 1) ? b : (g == 2) ? c : d;
  const float4 v0 = ((const float4*)s)[j * 2];
  const float4 v1 = ((const float4*)s)[j * 2 + 1];
  bf16x8 ov = {(bf16)v0.x, (bf16)v0.y, (bf16)v0.z, (bf16)v0.w,
               (bf16)v1.x, (bf16)v1.y, (bf16)v1.z, (bf16)v1.w};
  ((bf16x8*)o)[i] = ov;
}

// ---------------------------------------------------------------------------
// bf16 NT GEMM, m97 structure: global_load_lds staging + XOR swizzle.
// C[M,1024] = (A[M,1024] @ W[1024,1024]^T + bias) * oscale
// OUT_MODE 0: fp32 row-major; 1: bf16 head-major [B,NH,LQ,64];
// OUT_MODE 3: V^T flipped orientation — A=Wv (rows=d), W=x_low (rows=token),
//             bias indexed by ROW, out[((tok>>10)*1024 + row)*1024 + (tok&1023)]
//             -> coalesced 32B runs instead of 2KB-stride 2B scatter.
// LQ is COMPILE-TIME (pow2): row/LQ and row%LQ fold to shift/mask — the
// runtime-divisor version cost ~64 integer divisions per lane in the epilogue.
// Swizzle: 16B chunk qc of tile-row r lives at LDS slot (r, qc ^ (r&7)).
// ---------------------------------------------------------------------------
template <int OUT_MODE, int LQ>
__global__ __launch_bounds__(256) void gemm_bf16(const bf16* __restrict__ A,
                                                 const bf16* __restrict__ W,
                                                 const float* __restrict__ bias,
                                                 void* __restrict__ Cptr,
                                                 float oscale) {
  constexpr int LQS = ilog2(LQ);
  __shared__ bf16 As[128 * 64];
  __shared__ bf16 Bs[128 * 64];

  const int bm = blockIdx.x * 128;
  const int bn = blockIdx.y * 128;
  const int tid = threadIdx.x;
  const int w = tid >> 6;
  const int lane = tid & 63;
  const int quad = lane >> 4;
  const int l16 = lane & 15;
  const int wm = (w >> 1) * 64;
  const int wn = (w & 1) * 64;
  const int lr = lane >> 3;                 // row offset within a stage call
  const int sc8 = (((lane & 7) ^ lr)) << 3; // swizzled source chunk (elems)
  const int x7 = l16 & 7;

  // per-lane global element offsets for the 4 stage rounds (A and B)
  size_t aOff[4], bOff[4];
#pragma unroll
  for (int r = 0; r < 4; ++r) {
    const int rowt = (r * 4 + w) * 8 + lr;
    aOff[r] = (size_t)(bm + rowt) * DIM + sc8;
    bOff[r] = (size_t)(bn + rowt) * DIM + sc8;
  }

  f32x4 acc[4][4] = {};

  for (int k0 = 0; k0 < DIM; k0 += 64) {
#pragma unroll
    for (int r = 0; r < 4; ++r) {
      gl_lds16(A + aOff[r] + k0, (char*)As + (r * 4 + w) * 1024);
      gl_lds16(W + bOff[r] + k0, (char*)Bs + (r * 4 + w) * 1024);
    }
    __syncthreads();  // vmcnt(0) drain -> tile resident

#pragma unroll
    for (int s = 0; s < 2; ++s) {
      bf16x8 af[4], bfr[4];
#pragma unroll
      for (int mi = 0; mi < 4; ++mi)
        af[mi] = *(const bf16x8*)((char*)As + (wm + mi * 16 + l16) * 128 +
                                  (((quad + 4 * s) ^ x7) << 4));
#pragma unroll
      for (int ni = 0; ni < 4; ++ni)
        bfr[ni] = *(const bf16x8*)((char*)Bs + (wn + ni * 16 + l16) * 128 +
                                   (((quad + 4 * s) ^ x7) << 4));
#pragma unroll
      for (int mi = 0; mi < 4; ++mi)
#pragma unroll
        for (int ni = 0; ni < 4; ++ni)
          acc[mi][ni] = MFMA16(af[mi], bfr[ni], acc[mi][ni]);
    }
    __syncthreads();  // reads done before next overwrite
  }

  // hoisted per-column bias (OUT_MODE 0/1)
  float bcol[4];
#pragma unroll
  for (int ni = 0; ni < 4; ++ni)
    bcol[ni] = (OUT_MODE == 3) ? 0.f : bias[bn + wn + ni * 16 + l16];

#pragma unroll
  for (int mi = 0; mi < 4; ++mi) {
    // hoisted per-row bias (OUT_MODE 3)
    float brow[4];
    if constexpr (OUT_MODE == 3) {
#pragma unroll
      for (int r = 0; r < 4; ++r) brow[r] = bias[bm + wm + mi * 16 + quad * 4 + r];
    }
#pragma unroll
    for (int ni = 0; ni < 4; ++ni) {
      const int col = bn + wn + ni * 16 + l16;
#pragma unroll
      for (int r = 0; r < 4; ++r) {
        const int row = bm + wm + mi * 16 + quad * 4 + r;
        if constexpr (OUT_MODE == 0) {
          const float val = (acc[mi][ni][r] + bcol[ni]) * oscale;
          ((float*)Cptr)[(size_t)row * DIM + col] = val;
        } else if constexpr (OUT_MODE == 1) {
          const float val = (acc[mi][ni][r] + bcol[ni]) * oscale;
          const int b = row >> LQS;           // pow2: shift, not divide
          const int l = row & (LQ - 1);
          ((bf16*)Cptr)[((((size_t)(b * NH + (col >> 6)) << LQS) + l) << 6) +
                        (col & 63)] = (bf16)val;
        } else {  // OUT_MODE 3: V^T, row = d-index, col = global token
          const float val = acc[mi][ni][r] + brow[r];
          const int bb = col >> 10;
          const int kv = col & 1023;
          ((bf16*)Cptr)[((size_t)(bb * 1024 + row)) * 1024 + kv] = (bf16)val;
        }
      }
    }
  }
}

// ---------------------------------------------------------------------------
// Legacy fp32-input GEMM (R3) — fallback when ws is too small for bf16 path.
// ---------------------------------------------------------------------------
template <int OUT_MODE, bool A_BF16>
__global__ __launch_bounds__(256) void gemm_nt(const void* __restrict__ Aptr,
                                               const float* __restrict__ W,
                                               const float* __restrict__ bias,
                                               void* __restrict__ Cptr, int Lq,
                                               float oscale) {
  constexpr int LDT = 72;
  __shared__ bf16 As[128 * LDT];
  __shared__ bf16 Bs[128 * LDT];

  const int bm = blockIdx.x * 128;
  const int bn = blockIdx.y * 128;
  const int tid = threadIdx.x;
  const int w = tid >> 6;
  const int lane = tid & 63;
  const int quad = lane >> 4;
  const int l16 = lane & 15;
  const int wm = (w >> 1) * 64;
  const int wn = (w & 1) * 64;

  f32x4 acc[4][4] = {};

  for (int k0 = 0; k0 < DIM; k0 += 64) {
#pragma unroll
    for (int i = 0; i < 8; ++i) {
      int f = i * 256 + tid;
      int row = f >> 4;
      int c4 = (f & 15) << 2;
      const float4 v = *(const float4*)(W + (size_t)(bn + row) * DIM + k0 + c4);
      bf16x4 bv = {(bf16)v.x, (bf16)v.y, (bf16)v.z, (bf16)v.w};
      *(bf16x4*)&Bs[row * LDT + c4] = bv;
    }
    if constexpr (A_BF16) {
      const bf16* Ab = (const bf16*)Aptr;
#pragma unroll
      for (int i = 0; i < 4; ++i) {
        int f = i * 256 + tid;
        int row = f >> 3;
        int c8 = (f & 7) << 3;
        *(bf16x8*)&As[row * LDT + c8] =
            *(const bf16x8*)(Ab + (size_t)(bm + row) * DIM + k0 + c8);
      }
    } else {
      const float* Af = (const float*)Aptr;
#pragma unroll
      for (int i = 0; i < 8; ++i) {
        int f = i * 256 + tid;
        int row = f >> 4;
        int c4 = (f & 15) << 2;
        const float4 v = *(const float4*)(Af + (size_t)(bm + row) * DIM + k0 + c4);
        bf16x4 av = {(bf16)v.x, (bf16)v.y, (bf16)v.z, (bf16)v.w};
        *(bf16x4*)&As[row * LDT + c4] = av;
      }
    }
    __syncthreads();

#pragma unroll
    for (int sub = 0; sub < 2; ++sub) {
      bf16x8 af[4], bfr[4];
#pragma unroll
      for (int mi = 0; mi < 4; ++mi)
        af[mi] = *(const bf16x8*)&As[(wm + mi * 16 + l16) * LDT + sub * 32 + quad * 8];
#pragma unroll
      for (int ni = 0; ni < 4; ++ni)
        bfr[ni] = *(const bf16x8*)&Bs[(wn + ni * 16 + l16) * LDT + sub * 32 + quad * 8];
#pragma unroll
      for (int mi = 0; mi < 4; ++mi)
#pragma unroll
        for (int ni = 0; ni < 4; ++ni)
          acc[mi][ni] = MFMA16(af[mi], bfr[ni], acc[mi][ni]);
    }
    __syncthreads();
  }

#pragma unroll
  for (int mi = 0; mi < 4; ++mi) {
#pragma unroll
    for (int ni = 0; ni < 4; ++ni) {
      const int col = bn + wn + ni * 16 + l16;
      const float bv = bias[col];
#pragma unroll
      for (int r = 0; r < 4; ++r) {
        const int row = bm + wm + mi * 16 + quad * 4 + r;
        const float val = (acc[mi][ni][r] + bv) * oscale;
        if constexpr (OUT_MODE == 0) {
          ((float*)Cptr)[(size_t)row * DIM + col] = val;
        } else if constexpr (OUT_MODE == 1) {
          const int b = row / Lq;
          const int l = row - b * Lq;
          ((bf16*)Cptr)[((size_t)((b * NH + (col >> 6)) * Lq + l) << 6) + (col & 63)] =
              (bf16)val;
        } else {
          const int b = row >> 10;
          const int kv = row & 1023;
          ((bf16*)Cptr)[(((size_t)(b * NH + (col >> 6)) << 6) + (col & 63)) * 1024 + kv] =
              (bf16)val;
        }
      }
    }
  }
}

// ---------------------------------------------------------------------------
// Flash cross-attention, transposed formulation, LDS-staged K/V.
//   S^T = K Q^T ; O^T = V^T P^T. 128 q rows/block, 4 waves x 2 q-groups.
//   Q comes in pre-scaled by SCALE*log2(e), so softmax is exp2(S) directly.
//   K,V^T 64x64 tiles double-buffered in LDS via swizzled global_load_lds.
//   P scratch: one 16x64 per-wave XOR-swizzled buffer SHARED by both q-groups
//   (in-wave LDS ordering makes write->read->overwrite safe). LDS total
//   40960 B -> 4 blocks/CU.
//   Softmax denominator via ones-MFMA on the matrix pipe.
// grid (4096/128, NH, B), 256 threads.  [R3's QBLK=256 regressed: reverted]
// ---------------------------------------------------------------------------
__global__ __launch_bounds__(256) void attn_fused(const bf16* __restrict__ Q,
                                                  const bf16* __restrict__ K,
                                                  const bf16* __restrict__ VT,
                                                  bf16* __restrict__ O) {
  __shared__ bf16 Ks[2][64 * 64];
  __shared__ bf16 Vs[2][64 * 64];
  __shared__ bf16 Ps[4 * 16 * 64];  // per-wave 16x64, swizzled, group-shared

  const int qt = blockIdx.x;
  const int h = blockIdx.y;
  const int b = blockIdx.z;
  const int tid = threadIdx.x;
  const int w = tid >> 6;
  const int lane = tid & 63;
  const int quad = lane >> 4;
  const int l16 = lane & 15;
  const int lr = lane >> 3;
  const int sc8 = (((lane & 7) ^ lr)) << 3;
  const int x7 = l16 & 7;

  const bf16* Qp = Q + ((size_t)(b * NH + h) * 4096 + qt * 128 + w * 32 + l16) * HD + quad * 8;
  const bf16* Kb = K + (size_t)(b * NH + h) * 1024 * HD;
  const bf16* Vb = VT + (size_t)(b * NH + h) * HD * 1024;

  bf16x8 qf[2][2];
#pragma unroll
  for (int g = 0; g < 2; ++g)
#pragma unroll
    for (int s = 0; s < 2; ++s) qf[g][s] = *(const bf16x8*)(Qp + g * 16 * HD + s * 32);

  char* pw = (char*)&Ps[w * 16 * 64];

  f32x4 oacc[2][4] = {};
  f32x4 lacc[2] = {};  // softmax denominator, accumulated on MFMA pipe

  bf16x8 ones;
#pragma unroll
  for (int i = 0; i < 8; ++i) ones[i] = (bf16)1.0f;

  auto stage = [&](int kt, int bi) {
#pragma unroll
    for (int c2 = 0; c2 < 2; ++c2) {
      const int c = c2 * 4 + w;
      gl_lds16(Kb + (size_t)(kt + c * 8 + lr) * HD + sc8, (char*)&Ks[bi][0] + c * 1024);
      gl_lds16(Vb + (size_t)(c * 8 + lr) * 1024 + kt + sc8, (char*)&Vs[bi][0] + c * 1024);
    }
  };

  stage(0, 0);
  int buf = 0;
  for (int kt = 0; kt < 1024; kt += 64) {
    __syncthreads();  // drains this tile's global_load_lds (vmcnt0) + syncs waves
    if (kt + 64 < 1024) stage(kt + 64, buf ^ 1);

    // ---- K fragments (shared by both q-groups), swizzled LDS reads
    bf16x8 kf[4][2];
#pragma unroll
    for (int nt = 0; nt < 4; ++nt)
#pragma unroll
      for (int s = 0; s < 2; ++s)
        kf[nt][s] = *(const bf16x8*)((char*)&Ks[buf][0] + (nt * 16 + l16) * 128 +
                                     (((quad + 4 * s) ^ x7) << 4));

    // ---- per group: S^T + exp2 + swizzled P store, then P^T B-fragments
    bf16x8 pf[2][2];
#pragma unroll
    for (int g = 0; g < 2; ++g) {
      __builtin_amdgcn_s_setprio(1);
#pragma unroll
      for (int nt = 0; nt < 4; ++nt) {
        f32x4 a = {0.f, 0.f, 0.f, 0.f};
        a = MFMA16(kf[nt][0], qf[g][0], a);
        a = MFMA16(kf[nt][1], qf[g][1], a);
        bf16x4 pb;
#pragma unroll
        for (int r = 0; r < 4; ++r) pb[r] = (bf16)fast_exp2(a[r]);
        *(bf16x4*)(pw + l16 * 128 + ((nt * 32 + quad * 8) ^ (x7 << 4))) = pb;
      }
      __builtin_amdgcn_s_setprio(0);
#pragma unroll
      for (int s = 0; s < 2; ++s)
        pf[g][s] = *(const bf16x8*)(pw + l16 * 128 + ((s * 64 + quad * 16) ^ (x7 << 4)));
      // denominator: l[q] += sum_kv P (rows of C all identical = column sums)
      lacc[g] = MFMA16(ones, pf[g][0], lacc[g]);
      lacc[g] = MFMA16(ones, pf[g][1], lacc[g]);
    }

    // ---- V^T fragments + O^T += V^T P^T
    __builtin_amdgcn_s_setprio(1);
#pragma unroll
    for (int dt = 0; dt < 4; ++dt) {
      bf16x8 vf0 = *(const bf16x8*)((char*)&Vs[buf][0] + (dt * 16 + l16) * 128 +
                                    ((quad ^ x7) << 4));
      bf16x8 vf1 = *(const bf16x8*)((char*)&Vs[buf][0] + (dt * 16 + l16) * 128 +
                                    ((((quad + 4)) ^ x7) << 4));
      oacc[0][dt] = MFMA16(vf0, pf[0][0], oacc[0][dt]);
      oacc[0][dt] = MFMA16(vf1, pf[0][1], oacc[0][dt]);
      oacc[1][dt] = MFMA16(vf0, pf[1][0], oacc[1][dt]);
      oacc[1][dt] = MFMA16(vf1, pf[1][1], oacc[1][dt]);
    }
    __builtin_amdgcn_s_setprio(0);
    buf ^= 1;
  }

  // ---- finalize (lacc rows are identical: every lane already holds its
  // column's full denominator — no cross-lane reduce needed)
  const float inv[2] = {1.f / lacc[0][0], 1.f / lacc[1][0]};

#pragma unroll
  for (int g = 0; g < 2; ++g) {
    const size_t orow =
        ((size_t)(b * 4096 + qt * 128 + w * 32 + g * 16 + l16)) * DIM + h * 64;
#pragma unroll
    for (int dt = 0; dt < 4; ++dt) {
      bf16x4 ov = {(bf16)(oacc[g][dt][0] * inv[g]), (bf16)(oacc[g][dt][1] * inv[g]),
                   (bf16)(oacc[g][dt][2] * inv[g]), (bf16)(oacc[g][dt][3] * inv[g])};
      *(bf16x4*)(O + orow + dt * 16 + quad * 4) = ov;
    }
  }
}

// ---------------------------------------------------------------------------
extern "C" void kernel_launch(void* const* d_in, const int* in_sizes, int n_in,
                              void* d_out, int out_size, void* d_ws, size_t ws_size,
                              hipStream_t stream) {
  const float* x_broad = (const float*)d_in[0];
  const float* x_low = (const float*)d_in[1];
  const float* Wq = (const float*)d_in[2];
  const float* bq = (const float*)d_in[3];
  const float* Wk = (const float*)d_in[4];
  const float* bk = (const float*)d_in[5];
  const float* Wv = (const float*)d_in[6];
  const float* bv = (const float*)d_in[7];
  const float* Wo = (const float*)d_in[8];
  const float* bo = (const float*)d_in[9];

  constexpr int B = 4, L = 4096, LL = 1024;
  const size_t qBytes = (size_t)B * NH * L * HD * 2;    // 33.55 MB
  const size_t kvBytes = (size_t)B * NH * LL * HD * 2;  //  8.39 MB
  const size_t oBytes = qBytes;                          // 33.55 MB (O / xb_bf alias)
  const size_t xlBytes = kvBytes;                        //  8.39 MB
  const size_t wBytes = (size_t)DIM * DIM * 2;           //  2.10 MB each

  char* ws = (char*)d_ws;
  bf16* Qw = (bf16*)ws;
  bf16* Kw = (bf16*)(ws + qBytes);
  bf16* Vw = (bf16*)(ws + qBytes + kvBytes);
  bf16* Ow = (bf16*)(ws + qBytes + 2 * kvBytes);

  const dim3 blk(256);
  const size_t need = qBytes + 2 * kvBytes + oBytes + xlBytes + 4 * wBytes;

  if (ws_size >= need) {
    // bf16 fast path: Ow region doubles as xb_bf (consumed by Q-proj before attn writes O)
    bf16* xbB = Ow;
    bf16* xlB = (bf16*)(ws + qBytes + 2 * kvBytes + oBytes);
    bf16* WqB = (bf16*)(ws + qBytes + 2 * kvBytes + oBytes + xlBytes);
    bf16* WkB = WqB + (size_t)DIM * DIM;
    bf16* WvB = WkB + (size_t)DIM * DIM;
    bf16* WoB = WvB + (size_t)DIM * DIM;

    hipLaunchKernelGGL(cvt_f32_bf16, dim3(B * L * DIM / 8 / 256), blk, 0, stream,
                       x_broad, xbB, B * L * DIM / 8);
    hipLaunchKernelGGL(cvt_f32_bf16, dim3(B * LL * DIM / 8 / 256), blk, 0, stream,
                       x_low, xlB, B * LL * DIM / 8);
    hipLaunchKernelGGL(cvt_w4, dim3(4 * DIM * DIM / 8 / 256), blk, 0, stream, Wq, Wk,
                       Wv, Wo, WqB);

    // Q-projection carries the softmax scale (SCALE*log2e) in its epilogue
    hipLaunchKernelGGL((gemm_bf16<1, L>), dim3(B * L / 128, DIM / 128), blk, 0, stream,
                       xbB, WqB, bq, Qw, SCL2E);
    hipLaunchKernelGGL((gemm_bf16<1, LL>), dim3(B * LL / 128, DIM / 128), blk, 0,
                       stream, xlB, WkB, bk, Kw, 1.0f);
    // V^T via flipped orientation: A = Wv (rows=d), B = x_low (rows=token)
    hipLaunchKernelGGL((gemm_bf16<3, 1>), dim3(DIM / 128, B * LL / 128), blk, 0,
                       stream, WvB, xlB, bv, Vw, 1.0f);
    hipLaunchKernelGGL(attn_fused, dim3(L / 128, NH, B), blk, 0, stream, Qw, Kw, Vw, Ow);
    hipLaunchKernelGGL((gemm_bf16<0, 1>), dim3(B * L / 128, DIM / 128), blk, 0, stream,
                       Ow, WoB, bo, d_out, 1.0f);
  } else {
    // fallback: fp32-input GEMMs (R3), same attention
    hipLaunchKernelGGL((gemm_nt<1, false>), dim3(B * L / 128, DIM / 128), blk, 0,
                       stream, x_broad, Wq, bq, Qw, L, SCL2E);
    hipLaunchKernelGGL((gemm_nt<1, false>), dim3(B * LL / 128, DIM / 128), blk, 0,
                       stream, x_low, Wk, bk, Kw, LL, 1.0f);
    hipLaunchKernelGGL((gemm_nt<2, false>), dim3(B * LL / 128, DIM / 128), blk, 0,
                       stream, x_low, Wv, bv, Vw, LL, 1.0f);
    hipLaunchKernelGGL(attn_fused, dim3(L / 128, NH, B), blk, 0, stream, Qw, Kw, Vw, Ow);
    hipLaunchKernelGGL((gemm_nt<0, true>), dim3(B * L / 128, DIM / 128), blk, 0,
                       stream, Ow, Wo, bo, d_out, 1, 1.0f);
  }
}

// Round 5
// 370.922 us; speedup vs baseline: 1.0131x; 1.0002x over previous
//
#include <hip/hip_runtime.h>
#include <hip/hip_bf16.h>

typedef __bf16 bf16;
typedef __bf16 bf16x4 __attribute__((ext_vector_type(4)));
typedef __bf16 bf16x8 __attribute__((ext_vector_type(8)));
typedef float f32x4 __attribute__((ext_vector_type(4)));

#define MFMA16(a, b, c) __builtin_amdgcn_mfma_f32_16x16x32_bf16(a, b, c, 0, 0, 0)

constexpr int DIM = 1024;
constexpr int NH = 16;
constexpr int HD = 64;
constexpr float SCALE = 0.125f;
constexpr float L2E = 1.4426950408889634f;
constexpr float SCL2E = SCALE * L2E;  // folded into Q-proj epilogue

constexpr int ilog2(int v) {
  int s = 0;
  while ((1 << s) < v) ++s;
  return s;
}

// raw v_exp_f32 — bypass the denorm-guarded exp2f lowering
__device__ __forceinline__ float fast_exp2(float x) {
  float r;
  asm("v_exp_f32 %0, %1" : "=v"(r) : "v"(x));
  return r;
}

// async global->LDS, 16B per lane; lane i deposits at ldsbase + i*16
__device__ __forceinline__ void gl_lds16(const void* g, void* l) {
  __builtin_amdgcn_global_load_lds((const __attribute__((address_space(1))) void*)g,
                                   (__attribute__((address_space(3))) void*)l, 16, 0, 0);
}

// ---------------------------------------------------------------------------
// fp32 -> bf16 conversion (memory-bound, vectorized 8/thread)
// ---------------------------------------------------------------------------
__global__ __launch_bounds__(256) void cvt_f32_bf16(const float* __restrict__ s,
                                                    bf16* __restrict__ d, int n8) {
  const int i = blockIdx.x * 256 + threadIdx.x;
  if (i < n8) {
    const float4 v0 = ((const float4*)s)[i * 2];
    const float4 v1 = ((const float4*)s)[i * 2 + 1];
    bf16x8 o = {(bf16)v0.x, (bf16)v0.y, (bf16)v0.z, (bf16)v0.w,
                (bf16)v1.x, (bf16)v1.y, (bf16)v1.z, (bf16)v1.w};
    ((bf16x8*)d)[i] = o;
  }
}

// all 4 weight matrices in one launch; dst regions are contiguous in ws
__global__ __launch_bounds__(256) void cvt_w4(const float* __restrict__ a,
                                              const float* __restrict__ b,
                                              const float* __restrict__ c,
                                              const float* __restrict__ d,
                                              bf16* __restrict__ o) {
  constexpr int N8 = DIM * DIM / 8;  // 131072 (pow2)
  const int i = blockIdx.x * 256 + threadIdx.x;  // grid covers 4*N8 exactly
  const int g = i >> 17;
  const int j = i & (N8 - 1);
  const float* s = (g == 0) ? a : (g == 1) ? b : (g == 2) ? c : d;
  const float4 v0 = ((const float4*)s)[j * 2];
  const float4 v1 = ((const float4*)s)[j * 2 + 1];
  bf16x8 ov = {(bf16)v0.x, (bf16)v0.y, (bf16)v0.z, (bf16)v0.w,
               (bf16)v1.x, (bf16)v1.y, (bf16)v1.z, (bf16)v1.w};
  ((bf16x8*)o)[i] = ov;
}

// ---------------------------------------------------------------------------
// BIG bf16 NT GEMM for M=16384 shapes (Q-proj / O-proj).
// 256x256 tile, BK=32, 512 threads (8 waves, 4M x 2N -> 64x64 per wave).
// 3-buffer LDS rotation + counted vmcnt — loads stay in flight across the
// single per-tile barrier (T4).  Race-free by construction:
//   iter t: [vmcnt(4): tile t landed] [barrier: all waves done reading
//   buf (t-1)%3] [stage(t+2) -> buf (t+2)%3 == (t-1)%3] [compute buf t%3].
// Swizzle: 16B chunk c of row r lives at slot c ^ (r&3) (4 chunks/row of 64B).
// ---------------------------------------------------------------------------
template <int OUT_MODE, int LQ>  // 0: fp32 row-major; 1: bf16 head-major
__global__ __launch_bounds__(512) void gemm_big(const bf16* __restrict__ A,
                                                const bf16* __restrict__ W,
                                                const float* __restrict__ bias,
                                                void* __restrict__ Cptr,
                                                float oscale) {
  constexpr int LQS = ilog2(LQ);
  __shared__ bf16 Ls[3][2][256 * 32];  // [buf][A/B][row*32+col]  96 KiB

  const int bm = blockIdx.x * 256;
  const int bn = blockIdx.y * 256;
  const int tid = threadIdx.x;
  const int w = tid >> 6;
  const int lane = tid & 63;
  const int quad = lane >> 4;
  const int l16 = lane & 15;
  const int wr = w >> 1;   // 0..3  (M)
  const int wc = w & 1;    // 0..1  (N)
  const int lr4 = lane >> 2;                       // 0..15 row in 16-row group
  const int c4 = ((lane & 3) ^ (lr4 & 3)) << 3;    // swizzled chunk (elems)

  // per-lane global element offsets for the 2 stage issues (A and B)
  int aS[2], bS[2];
#pragma unroll
  for (int i = 0; i < 2; ++i) {
    const int rr = (i * 8 + w) * 16 + lr4;
    aS[i] = (bm + rr) * DIM + c4;
    bS[i] = (bn + rr) * DIM + c4;
  }

  auto stage = [&](int t, int bi) {
#pragma unroll
    for (int i = 0; i < 2; ++i) {
      gl_lds16(A + aS[i] + t * 32, (char*)&Ls[bi][0][0] + (i * 8 + w) * 1024);
      gl_lds16(W + bS[i] + t * 32, (char*)&Ls[bi][1][0] + (i * 8 + w) * 1024);
    }
  };

  f32x4 acc[8][4] = {};  // wave computes 128(M) x 64(N): wr*64 rows? no:
  // per-wave: rows wr*64*... M split: 4 waves x 64 rows? We use 4M x 2N:
  // rows = wr*64 .. +64  (M_rep=4? )  -- see below: M_rep=8 needs 2M split.
  // Correction: 4M x 2N over 256x256 -> per-wave 64 rows x 128 cols.
  // We keep acc[8][4] as [ni up to 8?]: simpler to define per-wave 64x128:
  // M_rep=4 (mi<4), N_rep=8 (ni<8) -> acc[mi][ni] with mi<4, ni<8.
  // To keep array dims aligned with loops we use acc[8][4] as acc[ni][mi].

  const int rowBase = wr * 64;    // wave's M offset (64 rows)
  const int colBase = wc * 128;   // wave's N offset (128 cols)

  stage(0, 0);
  stage(1, 1);

  int bi = 0;
  for (int t = 0; t < 32; ++t) {
    if (t < 31)
      asm volatile("s_waitcnt vmcnt(4)" ::: "memory");
    else
      asm volatile("s_waitcnt vmcnt(0)" ::: "memory");
    __builtin_amdgcn_s_barrier();
    __builtin_amdgcn_sched_barrier(0);

    if (t + 2 < 32) stage(t + 2, bi == 0 ? 2 : bi - 1);

    const char* baseA = (const char*)&Ls[bi][0][0];
    const char* baseB = (const char*)&Ls[bi][1][0];
    const int sw = ((quad ^ (l16 & 3)) << 4);

    bf16x8 af[4], bfr[8];
#pragma unroll
    for (int mi = 0; mi < 4; ++mi)
      af[mi] = *(const bf16x8*)(baseA + (rowBase + mi * 16 + l16) * 64 + sw);
#pragma unroll
    for (int ni = 0; ni < 8; ++ni)
      bfr[ni] = *(const bf16x8*)(baseB + (colBase + ni * 16 + l16) * 64 + sw);

    __builtin_amdgcn_s_setprio(1);
#pragma unroll
    for (int ni = 0; ni < 8; ++ni)
#pragma unroll
      for (int mi = 0; mi < 4; ++mi)
        acc[ni][mi] = MFMA16(af[mi], bfr[ni], acc[ni][mi]);
    __builtin_amdgcn_s_setprio(0);

    bi = (bi == 2) ? 0 : bi + 1;
  }

  // epilogue: rows bm+rowBase+mi*16+quad*4+r ; cols bn+colBase+ni*16+l16
  float bcol[8];
#pragma unroll
  for (int ni = 0; ni < 8; ++ni) bcol[ni] = bias[bn + colBase + ni * 16 + l16];

#pragma unroll
  for (int ni = 0; ni < 8; ++ni) {
    const int col = bn + colBase + ni * 16 + l16;
#pragma unroll
    for (int mi = 0; mi < 4; ++mi) {
#pragma unroll
      for (int r = 0; r < 4; ++r) {
        const int row = bm + rowBase + mi * 16 + quad * 4 + r;
        const float val = (acc[ni][mi][r] + bcol[ni]) * oscale;
        if constexpr (OUT_MODE == 0) {
          ((float*)Cptr)[(size_t)row * DIM + col] = val;
        } else {
          const int b = row >> LQS;
          const int l = row & (LQ - 1);
          ((bf16*)Cptr)[((((size_t)(b * NH + (col >> 6)) << LQS) + l) << 6) +
                        (col & 63)] = (bf16)val;
        }
      }
    }
  }
}

// ---------------------------------------------------------------------------
// bf16 NT GEMM, m97 structure (128^2): kept for the small-M K/V projections.
// OUT_MODE 1: bf16 head-major; 3: V^T flipped orientation (bias by ROW).
// ---------------------------------------------------------------------------
template <int OUT_MODE, int LQ>
__global__ __launch_bounds__(256) void gemm_bf16(const bf16* __restrict__ A,
                                                 const bf16* __restrict__ W,
                                                 const float* __restrict__ bias,
                                                 void* __restrict__ Cptr,
                                                 float oscale) {
  constexpr int LQS = ilog2(LQ);
  __shared__ bf16 As[128 * 64];
  __shared__ bf16 Bs[128 * 64];

  const int bm = blockIdx.x * 128;
  const int bn = blockIdx.y * 128;
  const int tid = threadIdx.x;
  const int w = tid >> 6;
  const int lane = tid & 63;
  const int quad = lane >> 4;
  const int l16 = lane & 15;
  const int wm = (w >> 1) * 64;
  const int wn = (w & 1) * 64;
  const int lr = lane >> 3;
  const int sc8 = (((lane & 7) ^ lr)) << 3;
  const int x7 = l16 & 7;

  size_t aOff[4], bOff[4];
#pragma unroll
  for (int r = 0; r < 4; ++r) {
    const int rowt = (r * 4 + w) * 8 + lr;
    aOff[r] = (size_t)(bm + rowt) * DIM + sc8;
    bOff[r] = (size_t)(bn + rowt) * DIM + sc8;
  }

  f32x4 acc[4][4] = {};

  for (int k0 = 0; k0 < DIM; k0 += 64) {
#pragma unroll
    for (int r = 0; r < 4; ++r) {
      gl_lds16(A + aOff[r] + k0, (char*)As + (r * 4 + w) * 1024);
      gl_lds16(W + bOff[r] + k0, (char*)Bs + (r * 4 + w) * 1024);
    }
    __syncthreads();

#pragma unroll
    for (int s = 0; s < 2; ++s) {
      bf16x8 af[4], bfr[4];
#pragma unroll
      for (int mi = 0; mi < 4; ++mi)
        af[mi] = *(const bf16x8*)((char*)As + (wm + mi * 16 + l16) * 128 +
                                  (((quad + 4 * s) ^ x7) << 4));
#pragma unroll
      for (int ni = 0; ni < 4; ++ni)
        bfr[ni] = *(const bf16x8*)((char*)Bs + (wn + ni * 16 + l16) * 128 +
                                   (((quad + 4 * s) ^ x7) << 4));
#pragma unroll
      for (int mi = 0; mi < 4; ++mi)
#pragma unroll
        for (int ni = 0; ni < 4; ++ni)
          acc[mi][ni] = MFMA16(af[mi], bfr[ni], acc[mi][ni]);
    }
    __syncthreads();
  }

  float bcol[4];
#pragma unroll
  for (int ni = 0; ni < 4; ++ni)
    bcol[ni] = (OUT_MODE == 3) ? 0.f : bias[bn + wn + ni * 16 + l16];

#pragma unroll
  for (int mi = 0; mi < 4; ++mi) {
    float brow[4];
    if constexpr (OUT_MODE == 3) {
#pragma unroll
      for (int r = 0; r < 4; ++r) brow[r] = bias[bm + wm + mi * 16 + quad * 4 + r];
    }
#pragma unroll
    for (int ni = 0; ni < 4; ++ni) {
      const int col = bn + wn + ni * 16 + l16;
#pragma unroll
      for (int r = 0; r < 4; ++r) {
        const int row = bm + wm + mi * 16 + quad * 4 + r;
        if constexpr (OUT_MODE == 0) {
          const float val = (acc[mi][ni][r] + bcol[ni]) * oscale;
          ((float*)Cptr)[(size_t)row * DIM + col] = val;
        } else if constexpr (OUT_MODE == 1) {
          const float val = (acc[mi][ni][r] + bcol[ni]) * oscale;
          const int b = row >> LQS;
          const int l = row & (LQ - 1);
          ((bf16*)Cptr)[((((size_t)(b * NH + (col >> 6)) << LQS) + l) << 6) +
                        (col & 63)] = (bf16)val;
        } else {  // OUT_MODE 3: V^T, row = d-index, col = global token
          const float val = acc[mi][ni][r] + brow[r];
          const int bb = col >> 10;
          const int kv = col & 1023;
          ((bf16*)Cptr)[((size_t)(bb * 1024 + row)) * 1024 + kv] = (bf16)val;
        }
      }
    }
  }
}

// ---------------------------------------------------------------------------
// Legacy fp32-input GEMM — fallback when ws is too small for bf16 path.
// ---------------------------------------------------------------------------
template <int OUT_MODE, bool A_BF16>
__global__ __launch_bounds__(256) void gemm_nt(const void* __restrict__ Aptr,
                                               const float* __restrict__ W,
                                               const float* __restrict__ bias,
                                               void* __restrict__ Cptr, int Lq,
                                               float oscale) {
  constexpr int LDT = 72;
  __shared__ bf16 As[128 * LDT];
  __shared__ bf16 Bs[128 * LDT];

  const int bm = blockIdx.x * 128;
  const int bn = blockIdx.y * 128;
  const int tid = threadIdx.x;
  const int w = tid >> 6;
  const int lane = tid & 63;
  const int quad = lane >> 4;
  const int l16 = lane & 15;
  const int wm = (w >> 1) * 64;
  const int wn = (w & 1) * 64;

  f32x4 acc[4][4] = {};

  for (int k0 = 0; k0 < DIM; k0 += 64) {
#pragma unroll
    for (int i = 0; i < 8; ++i) {
      int f = i * 256 + tid;
      int row = f >> 4;
      int c4 = (f & 15) << 2;
      const float4 v = *(const float4*)(W + (size_t)(bn + row) * DIM + k0 + c4);
      bf16x4 bv = {(bf16)v.x, (bf16)v.y, (bf16)v.z, (bf16)v.w};
      *(bf16x4*)&Bs[row * LDT + c4] = bv;
    }
    if constexpr (A_BF16) {
      const bf16* Ab = (const bf16*)Aptr;
#pragma unroll
      for (int i = 0; i < 4; ++i) {
        int f = i * 256 + tid;
        int row = f >> 3;
        int c8 = (f & 7) << 3;
        *(bf16x8*)&As[row * LDT + c8] =
            *(const bf16x8*)(Ab + (size_t)(bm + row) * DIM + k0 + c8);
      }
    } else {
      const float* Af = (const float*)Aptr;
#pragma unroll
      for (int i = 0; i < 8; ++i) {
        int f = i * 256 + tid;
        int row = f >> 4;
        int c4 = (f & 15) << 2;
        const float4 v = *(const float4*)(Af + (size_t)(bm + row) * DIM + k0 + c4);
        bf16x4 av = {(bf16)v.x, (bf16)v.y, (bf16)v.z, (bf16)v.w};
        *(bf16x4*)&As[row * LDT + c4] = av;
      }
    }
    __syncthreads();

#pragma unroll
    for (int sub = 0; sub < 2; ++sub) {
      bf16x8 af[4], bfr[4];
#pragma unroll
      for (int mi = 0; mi < 4; ++mi)
        af[mi] = *(const bf16x8*)&As[(wm + mi * 16 + l16) * LDT + sub * 32 + quad * 8];
#pragma unroll
      for (int ni = 0; ni < 4; ++ni)
        bfr[ni] = *(const bf16x8*)&Bs[(wn + ni * 16 + l16) * LDT + sub * 32 + quad * 8];
#pragma unroll
      for (int mi = 0; mi < 4; ++mi)
#pragma unroll
        for (int ni = 0; ni < 4; ++ni)
          acc[mi][ni] = MFMA16(af[mi], bfr[ni], acc[mi][ni]);
    }
    __syncthreads();
  }

#pragma unroll
  for (int mi = 0; mi < 4; ++mi) {
#pragma unroll
    for (int ni = 0; ni < 4; ++ni) {
      const int col = bn + wn + ni * 16 + l16;
      const float bv = bias[col];
#pragma unroll
      for (int r = 0; r < 4; ++r) {
        const int row = bm + wm + mi * 16 + quad * 4 + r;
        const float val = (acc[mi][ni][r] + bv) * oscale;
        if constexpr (OUT_MODE == 0) {
          ((float*)Cptr)[(size_t)row * DIM + col] = val;
        } else if constexpr (OUT_MODE == 1) {
          const int b = row / Lq;
          const int l = row - b * Lq;
          ((bf16*)Cptr)[((size_t)((b * NH + (col >> 6)) * Lq + l) << 6) + (col & 63)] =
              (bf16)val;
        } else {
          const int b = row >> 10;
          const int kv = row & 1023;
          ((bf16*)Cptr)[(((size_t)(b * NH + (col >> 6)) << 6) + (col & 63)) * 1024 + kv] =
              (bf16)val;
        }
      }
    }
  }
}

// ---------------------------------------------------------------------------
// Flash cross-attention (unchanged from R4): transposed formulation,
// LDS-staged K/V, 128 q rows/block, ones-MFMA denominator.
// ---------------------------------------------------------------------------
__global__ __launch_bounds__(256) void attn_fused(const bf16* __restrict__ Q,
                                                  const bf16* __restrict__ K,
                                                  const bf16* __restrict__ VT,
                                                  bf16* __restrict__ O) {
  __shared__ bf16 Ks[2][64 * 64];
  __shared__ bf16 Vs[2][64 * 64];
  __shared__ bf16 Ps[4 * 16 * 64];

  const int qt = blockIdx.x;
  const int h = blockIdx.y;
  const int b = blockIdx.z;
  const int tid = threadIdx.x;
  const int w = tid >> 6;
  const int lane = tid & 63;
  const int quad = lane >> 4;
  const int l16 = lane & 15;
  const int lr = lane >> 3;
  const int sc8 = (((lane & 7) ^ lr)) << 3;
  const int x7 = l16 & 7;

  const bf16* Qp = Q + ((size_t)(b * NH + h) * 4096 + qt * 128 + w * 32 + l16) * HD + quad * 8;
  const bf16* Kb = K + (size_t)(b * NH + h) * 1024 * HD;
  const bf16* Vb = VT + (size_t)(b * NH + h) * HD * 1024;

  bf16x8 qf[2][2];
#pragma unroll
  for (int g = 0; g < 2; ++g)
#pragma unroll
    for (int s = 0; s < 2; ++s) qf[g][s] = *(const bf16x8*)(Qp + g * 16 * HD + s * 32);

  char* pw = (char*)&Ps[w * 16 * 64];

  f32x4 oacc[2][4] = {};
  f32x4 lacc[2] = {};

  bf16x8 ones;
#pragma unroll
  for (int i = 0; i < 8; ++i) ones[i] = (bf16)1.0f;

  auto stage = [&](int kt, int bi) {
#pragma unroll
    for (int c2 = 0; c2 < 2; ++c2) {
      const int c = c2 * 4 + w;
      gl_lds16(Kb + (size_t)(kt + c * 8 + lr) * HD + sc8, (char*)&Ks[bi][0] + c * 1024);
      gl_lds16(Vb + (size_t)(c * 8 + lr) * 1024 + kt + sc8, (char*)&Vs[bi][0] + c * 1024);
    }
  };

  stage(0, 0);
  int buf = 0;
  for (int kt = 0; kt < 1024; kt += 64) {
    __syncthreads();
    if (kt + 64 < 1024) stage(kt + 64, buf ^ 1);

    bf16x8 kf[4][2];
#pragma unroll
    for (int nt = 0; nt < 4; ++nt)
#pragma unroll
      for (int s = 0; s < 2; ++s)
        kf[nt][s] = *(const bf16x8*)((char*)&Ks[buf][0] + (nt * 16 + l16) * 128 +
                                     (((quad + 4 * s) ^ x7) << 4));

    bf16x8 pf[2][2];
#pragma unroll
    for (int g = 0; g < 2; ++g) {
      __builtin_amdgcn_s_setprio(1);
#pragma unroll
      for (int nt = 0; nt < 4; ++nt) {
        f32x4 a = {0.f, 0.f, 0.f, 0.f};
        a = MFMA16(kf[nt][0], qf[g][0], a);
        a = MFMA16(kf[nt][1], qf[g][1], a);
        bf16x4 pb;
#pragma unroll
        for (int r = 0; r < 4; ++r) pb[r] = (bf16)fast_exp2(a[r]);
        *(bf16x4*)(pw + l16 * 128 + ((nt * 32 + quad * 8) ^ (x7 << 4))) = pb;
      }
      __builtin_amdgcn_s_setprio(0);
#pragma unroll
      for (int s = 0; s < 2; ++s)
        pf[g][s] = *(const bf16x8*)(pw + l16 * 128 + ((s * 64 + quad * 16) ^ (x7 << 4)));
      lacc[g] = MFMA16(ones, pf[g][0], lacc[g]);
      lacc[g] = MFMA16(ones, pf[g][1], lacc[g]);
    }

    __builtin_amdgcn_s_setprio(1);
#pragma unroll
    for (int dt = 0; dt < 4; ++dt) {
      bf16x8 vf0 = *(const bf16x8*)((char*)&Vs[buf][0] + (dt * 16 + l16) * 128 +
                                    ((quad ^ x7) << 4));
      bf16x8 vf1 = *(const bf16x8*)((char*)&Vs[buf][0] + (dt * 16 + l16) * 128 +
                                    ((((quad + 4)) ^ x7) << 4));
      oacc[0][dt] = MFMA16(vf0, pf[0][0], oacc[0][dt]);
      oacc[0][dt] = MFMA16(vf1, pf[0][1], oacc[0][dt]);
      oacc[1][dt] = MFMA16(vf0, pf[1][0], oacc[1][dt]);
      oacc[1][dt] = MFMA16(vf1, pf[1][1], oacc[1][dt]);
    }
    __builtin_amdgcn_s_setprio(0);
    buf ^= 1;
  }

  const float inv[2] = {1.f / lacc[0][0], 1.f / lacc[1][0]};

#pragma unroll
  for (int g = 0; g < 2; ++g) {
    const size_t orow =
        ((size_t)(b * 4096 + qt * 128 + w * 32 + g * 16 + l16)) * DIM + h * 64;
#pragma unroll
    for (int dt = 0; dt < 4; ++dt) {
      bf16x4 ov = {(bf16)(oacc[g][dt][0] * inv[g]), (bf16)(oacc[g][dt][1] * inv[g]),
                   (bf16)(oacc[g][dt][2] * inv[g]), (bf16)(oacc[g][dt][3] * inv[g])};
      *(bf16x4*)(O + orow + dt * 16 + quad * 4) = ov;
    }
  }
}

// ---------------------------------------------------------------------------
extern "C" void kernel_launch(void* const* d_in, const int* in_sizes, int n_in,
                              void* d_out, int out_size, void* d_ws, size_t ws_size,
                              hipStream_t stream) {
  const float* x_broad = (const float*)d_in[0];
  const float* x_low = (const float*)d_in[1];
  const float* Wq = (const float*)d_in[2];
  const float* bq = (const float*)d_in[3];
  const float* Wk = (const float*)d_in[4];
  const float* bk = (const float*)d_in[5];
  const float* Wv = (const float*)d_in[6];
  const float* bv = (const float*)d_in[7];
  const float* Wo = (const float*)d_in[8];
  const float* bo = (const float*)d_in[9];

  constexpr int B = 4, L = 4096, LL = 1024;
  const size_t qBytes = (size_t)B * NH * L * HD * 2;    // 33.55 MB
  const size_t kvBytes = (size_t)B * NH * LL * HD * 2;  //  8.39 MB
  const size_t oBytes = qBytes;                          // 33.55 MB (O / xb_bf alias)
  const size_t xlBytes = kvBytes;                        //  8.39 MB
  const size_t wBytes = (size_t)DIM * DIM * 2;           //  2.10 MB each

  char* ws = (char*)d_ws;
  bf16* Qw = (bf16*)ws;
  bf16* Kw = (bf16*)(ws + qBytes);
  bf16* Vw = (bf16*)(ws + qBytes + kvBytes);
  bf16* Ow = (bf16*)(ws + qBytes + 2 * kvBytes);

  const dim3 blk(256);
  const size_t need = qBytes + 2 * kvBytes + oBytes + xlBytes + 4 * wBytes;

  if (ws_size >= need) {
    // bf16 fast path: Ow region doubles as xb_bf (consumed by Q-proj before attn writes O)
    bf16* xbB = Ow;
    bf16* xlB = (bf16*)(ws + qBytes + 2 * kvBytes + oBytes);
    bf16* WqB = (bf16*)(ws + qBytes + 2 * kvBytes + oBytes + xlBytes);
    bf16* WkB = WqB + (size_t)DIM * DIM;
    bf16* WvB = WkB + (size_t)DIM * DIM;
    bf16* WoB = WvB + (size_t)DIM * DIM;

    hipLaunchKernelGGL(cvt_f32_bf16, dim3(B * L * DIM / 8 / 256), blk, 0, stream,
                       x_broad, xbB, B * L * DIM / 8);
    hipLaunchKernelGGL(cvt_f32_bf16, dim3(B * LL * DIM / 8 / 256), blk, 0, stream,
                       x_low, xlB, B * LL * DIM / 8);
    hipLaunchKernelGGL(cvt_w4, dim3(4 * DIM * DIM / 8 / 256), blk, 0, stream, Wq, Wk,
                       Wv, Wo, WqB);

    // big GEMMs (M=16384): 256^2 tile, counted-vmcnt 3-buffer pipeline
    hipLaunchKernelGGL((gemm_big<1, L>), dim3(B * L / 256, DIM / 256), dim3(512), 0,
                       stream, xbB, WqB, bq, Qw, SCL2E);
    // small GEMMs (M=4096 / 1024): 128^2 m97 structure
    hipLaunchKernelGGL((gemm_bf16<1, LL>), dim3(B * LL / 128, DIM / 128), blk, 0,
                       stream, xlB, WkB, bk, Kw, 1.0f);
    hipLaunchKernelGGL((gemm_bf16<3, 1>), dim3(DIM / 128, B * LL / 128), blk, 0,
                       stream, WvB, xlB, bv, Vw, 1.0f);
    hipLaunchKernelGGL(attn_fused, dim3(L / 128, NH, B), blk, 0, stream, Qw, Kw, Vw, Ow);
    hipLaunchKernelGGL((gemm_big<0, 1>), dim3(B * L / 256, DIM / 256), dim3(512), 0,
                       stream, Ow, WoB, bo, d_out, 1.0f);
  } else {
    // fallback: fp32-input GEMMs, same attention
    hipLaunchKernelGGL((gemm_nt<1, false>), dim3(B * L / 128, DIM / 128), blk, 0,
                       stream, x_broad, Wq, bq, Qw, L, SCL2E);
    hipLaunchKernelGGL((gemm_nt<1, false>), dim3(B * LL / 128, DIM / 128), blk, 0,
                       stream, x_low, Wk, bk, Kw, LL, 1.0f);
    hipLaunchKernelGGL((gemm_nt<2, false>), dim3(B * LL / 128, DIM / 128), blk, 0,
                       stream, x_low, Wv, bv, Vw, LL, 1.0f);
    hipLaunchKernelGGL(attn_fused, dim3(L / 128, NH, B), blk, 0, stream, Qw, Kw, Vw, Ow);
    hipLaunchKernelGGL((gemm_nt<0, true>), dim3(B * L / 128, DIM / 128), blk, 0,
                       stream, Ow, Wo, bo, d_out, 1, 1.0f);
  }
}